// Round 24
// baseline (136.247 us; speedup 1.0000x reference)
//
#include <hip/hip_runtime.h>
#include <math.h>

#define N 8192
#define FIN 129
#define D 64
#define KP 160                // padded K for layer-1 MFMA (129 -> 160)
#define TEMP 10.0f
#define LOG2E 1.4426950408889634f
#define SPLIT_S 32            // j-slices for stats passes (4 blk/CU, R18-validated)
#define SPLIT_W 32            // j-slices for write pass (4 blk/CU)
#define RG 4                  // row-groups per wave -> 64 rows/wave
#define BROWS 256             // 4 waves * 64 rows

typedef _Float16 f16x8 __attribute__((ext_vector_type(8)));
typedef _Float16 f16x4 __attribute__((ext_vector_type(4)));
typedef float    f32x4 __attribute__((ext_vector_type(4)));

#define MFMA16(A, B, C) __builtin_amdgcn_mfma_f32_16x16x32_f16((A), (B), (C), 0, 0, 0)

// Raw v_exp_f32 (2^x). Safe here: |x| <~ 30 (no-shift softmax bound).
static __device__ inline float fast_exp2(float x) {
#if __has_builtin(__builtin_amdgcn_exp2f)
    return __builtin_amdgcn_exp2f(x);
#else
    float r; asm("v_exp_f32 %0, %1" : "=v"(r) : "v"(x)); return r;
#endif
}

// Geometry (validated): mfma(A,B,acc) with A rows = base+lr, B rows = base+lr,
// both elems kf*32+8*lg -> C[row_B(lr)][col = Abase + lg*4 + e].
// MLP as MFMA GEMMs with hi/lo f16 split (x, W, h all split; 3-term products)
// -> f32-accurate q,k; stats/write passes byte-identical to R23.

// ---------------- prep: x -> padded hi/lo f16 [N][KP] ----------------
__global__ __launch_bounds__(256) void k_prep_x(
    const float* __restrict__ x, _Float16* __restrict__ xhi, _Float16* __restrict__ xlo)
{
    const int wave = threadIdx.x >> 6, lane = threadIdx.x & 63;
    const int r = blockIdx.x * 4 + wave;
    #pragma unroll
    for (int c0 = 0; c0 < KP; c0 += 64) {
        const int c = c0 + lane;
        if (c < KP) {
            const float v = (c < FIN) ? x[(size_t)r * FIN + c] : 0.f;
            const _Float16 h = (_Float16)v;
            xhi[(size_t)r * KP + c] = h;
            xlo[(size_t)r * KP + c] = (_Float16)(v - (float)h);
        }
    }
}

// ---------------- prep: transposed padded hi/lo weights ----------------
__global__ __launch_bounds__(256) void k_prep_w(
    const float* __restrict__ Wq1, const float* __restrict__ Wk1,
    const float* __restrict__ Wq2, const float* __restrict__ Wk2,
    _Float16* __restrict__ w1thi, _Float16* __restrict__ w1tlo,
    _Float16* __restrict__ w2thi, _Float16* __restrict__ w2tlo)
{
    for (int idx = threadIdx.x; idx < 2 * 64 * KP; idx += 256) {
        const int side = idx / (64 * KP);
        const int rem  = idx % (64 * KP);
        const int d = rem / KP, f = rem % KP;
        const float* W = side ? Wk1 : Wq1;
        const float v = (f < FIN) ? W[f * 64 + d] : 0.f;
        const _Float16 h = (_Float16)v;
        w1thi[idx] = h;
        w1tlo[idx] = (_Float16)(v - (float)h);
    }
    for (int idx = threadIdx.x; idx < 2 * 64 * 64; idx += 256) {
        const int side = idx / 4096;
        const int rem  = idx % 4096;
        const int d = rem / 64, t = rem % 64;
        const float* W = side ? Wk2 : Wq2;
        const float v = W[t * 64 + d];
        const _Float16 h = (_Float16)v;
        w2thi[idx] = h;
        w2tlo[idx] = (_Float16)(v - (float)h);
    }
}

// ---------------- MFMA MLP: 1 wave/block, 16 rows; grid (N/16, 2 sides) ----------------
__global__ __launch_bounds__(64) void k_mlp2(
    const _Float16* __restrict__ xhi, const _Float16* __restrict__ xlo,
    const _Float16* __restrict__ w1thi, const _Float16* __restrict__ w1tlo,
    const _Float16* __restrict__ w2thi, const _Float16* __restrict__ w2tlo,
    const float* __restrict__ bq1, const float* __restrict__ bk1,
    const float* __restrict__ bq2, const float* __restrict__ bk2,
    _Float16* __restrict__ qo, _Float16* __restrict__ ko)
{
    const int lane = threadIdx.x & 63;
    const int lr = lane & 15, lg = lane >> 4;
    const int r0 = blockIdx.x * 16;
    const int side = blockIdx.y;

    const _Float16* W1h = w1thi + side * (64 * KP);
    const _Float16* W1l = w1tlo + side * (64 * KP);
    const _Float16* W2h = w2thi + side * (64 * 64);
    const _Float16* W2l = w2tlo + side * (64 * 64);
    const float* b1 = side ? bk1 : bq1;
    const float* b2 = side ? bk2 : bq2;
    _Float16* out = side ? ko : qo;

    __shared__ _Float16 hh[16][80];   // padded stride: 16B-aligned, low conflicts
    __shared__ _Float16 hl[16][80];

    f16x8 bh[5], bl[5];
    #pragma unroll
    for (int kf = 0; kf < 5; ++kf) {
        bh[kf] = *reinterpret_cast<const f16x8*>(&xhi[(size_t)(r0 + lr) * KP + kf * 32 + 8 * lg]);
        bl[kf] = *reinterpret_cast<const f16x8*>(&xlo[(size_t)(r0 + lr) * KP + kf * 32 + 8 * lg]);
    }

    // layer 1: H = relu(X @ W1 + b1), 3-term split products
    #pragma unroll
    for (int rf = 0; rf < 4; ++rf) {
        f32x4 acc = {0.f, 0.f, 0.f, 0.f};
        #pragma unroll
        for (int kf = 0; kf < 5; ++kf) {
            const f16x8 ah = *reinterpret_cast<const f16x8*>(&W1h[(rf * 16 + lr) * KP + kf * 32 + 8 * lg]);
            const f16x8 al = *reinterpret_cast<const f16x8*>(&W1l[(rf * 16 + lr) * KP + kf * 32 + 8 * lg]);
            acc = MFMA16(al, bh[kf], acc);
            acc = MFMA16(ah, bl[kf], acc);
            acc = MFMA16(ah, bh[kf], acc);
        }
        const float4 bb = *reinterpret_cast<const float4*>(&b1[rf * 16 + lg * 4]);
        const float h0 = fmaxf(acc[0] + bb.x, 0.f);
        const float h1 = fmaxf(acc[1] + bb.y, 0.f);
        const float h2 = fmaxf(acc[2] + bb.z, 0.f);
        const float h3 = fmaxf(acc[3] + bb.w, 0.f);
        f16x4 vh, vl;
        vh[0] = (_Float16)h0; vl[0] = (_Float16)(h0 - (float)vh[0]);
        vh[1] = (_Float16)h1; vl[1] = (_Float16)(h1 - (float)vh[1]);
        vh[2] = (_Float16)h2; vl[2] = (_Float16)(h2 - (float)vh[2]);
        vh[3] = (_Float16)h3; vl[3] = (_Float16)(h3 - (float)vh[3]);
        *reinterpret_cast<f16x4*>(&hh[lr][rf * 16 + lg * 4]) = vh;
        *reinterpret_cast<f16x4*>(&hl[lr][rf * 16 + lg * 4]) = vl;
    }
    __syncthreads();

    // layer 2: Q = H @ W2 + b2
    f16x8 b2h[2], b2l[2];
    #pragma unroll
    for (int kf = 0; kf < 2; ++kf) {
        b2h[kf] = *reinterpret_cast<const f16x8*>(&hh[lr][kf * 32 + 8 * lg]);
        b2l[kf] = *reinterpret_cast<const f16x8*>(&hl[lr][kf * 32 + 8 * lg]);
    }
    #pragma unroll
    for (int rf = 0; rf < 4; ++rf) {
        f32x4 acc = {0.f, 0.f, 0.f, 0.f};
        #pragma unroll
        for (int kf = 0; kf < 2; ++kf) {
            const f16x8 ah = *reinterpret_cast<const f16x8*>(&W2h[(rf * 16 + lr) * 64 + kf * 32 + 8 * lg]);
            const f16x8 al = *reinterpret_cast<const f16x8*>(&W2l[(rf * 16 + lr) * 64 + kf * 32 + 8 * lg]);
            acc = MFMA16(al, b2h[kf], acc);
            acc = MFMA16(ah, b2l[kf], acc);
            acc = MFMA16(ah, b2h[kf], acc);
        }
        const float4 bb = *reinterpret_cast<const float4*>(&b2[rf * 16 + lg * 4]);
        f16x4 o;
        o[0] = (_Float16)(acc[0] + bb.x);
        o[1] = (_Float16)(acc[1] + bb.y);
        o[2] = (_Float16)(acc[2] + bb.z);
        o[3] = (_Float16)(acc[3] + bb.w);
        *reinterpret_cast<f16x4*>(&out[(size_t)(r0 + lr) * 64 + rf * 16 + lg * 4]) = o;
    }
}

// ---------------- Pass 1: raw row max -> mpart[SPLIT_S][N] (R23-exact) ----------------
__global__ __launch_bounds__(256) void k_max(
    const _Float16* __restrict__ q16, const _Float16* __restrict__ k16,
    float* __restrict__ mpart)
{
    const int tid  = threadIdx.x;
    const int wave = tid >> 6;
    const int lane = tid & 63;
    const int lr   = lane & 15;
    const int lg   = lane >> 4;
    const int i0   = blockIdx.x * BROWS + wave * 64;
    const int jbase = blockIdx.y * (N / SPLIT_S);

    f16x8 b[RG][2];
    #pragma unroll
    for (int rg = 0; rg < RG; ++rg) {
        b[rg][0] = *reinterpret_cast<const f16x8*>(&q16[(i0 + rg * 16 + lr) * D + 8 * lg]);
        b[rg][1] = *reinterpret_cast<const f16x8*>(&q16[(i0 + rg * 16 + lr) * D + 32 + 8 * lg]);
    }

    float mx[RG];
    #pragma unroll
    for (int rg = 0; rg < RG; ++rg) mx[rg] = -INFINITY;

    f16x8 a0[4], a1[4];
    #pragma unroll
    for (int s = 0; s < 3; ++s) {
        const int jr = jbase + s * 16;
        a0[s] = *reinterpret_cast<const f16x8*>(&k16[(jr + lr) * D + 8 * lg]);
        a1[s] = *reinterpret_cast<const f16x8*>(&k16[(jr + lr) * D + 32 + 8 * lg]);
    }

    #pragma unroll
    for (int s = 0; s < 16; ++s) {
        if (s + 3 < 16) {
            const int jr = jbase + (s + 3) * 16;
            a0[(s + 3) & 3] = *reinterpret_cast<const f16x8*>(&k16[(jr + lr) * D + 8 * lg]);
            a1[(s + 3) & 3] = *reinterpret_cast<const f16x8*>(&k16[(jr + lr) * D + 32 + 8 * lg]);
        }
        #pragma unroll
        for (int rg = 0; rg < RG; ++rg) {
            f32x4 acc = {0.f, 0.f, 0.f, 0.f};
            acc = MFMA16(a0[s & 3], b[rg][0], acc);
            acc = MFMA16(a1[s & 3], b[rg][1], acc);
            mx[rg] = fmaxf(mx[rg], fmaxf(fmaxf(acc[0], acc[1]), fmaxf(acc[2], acc[3])));
        }
    }

    #pragma unroll
    for (int rg = 0; rg < RG; ++rg) {
        mx[rg] = fmaxf(mx[rg], __shfl_xor(mx[rg], 16));
        mx[rg] = fmaxf(mx[rg], __shfl_xor(mx[rg], 32));
    }
    if (lane < 16) {
        #pragma unroll
        for (int rg = 0; rg < RG; ++rg)
            mpart[blockIdx.y * N + i0 + rg * 16 + lr] = mx[rg];
    }
}

// ---------------- Pass 2: Lpart (R23-exact) ----------------
__global__ __launch_bounds__(256) void k_sumL(
    const _Float16* __restrict__ q16, const _Float16* __restrict__ k16,
    const float* __restrict__ mpart, float* __restrict__ Lpart)
{
    const int tid  = threadIdx.x;
    const int wave = tid >> 6;
    const int lane = tid & 63;
    const int lr   = lane & 15;
    const int lg   = lane >> 4;
    const int i0   = blockIdx.x * BROWS + wave * 64;
    const int jbase = blockIdx.y * (N / SPLIT_S);

    __shared__ float rinv_s[N / SPLIT_S];
    {
        float m = mpart[jbase + tid];
        #pragma unroll
        for (int s = 1; s < SPLIT_S; ++s) m = fmaxf(m, mpart[s * N + jbase + tid]);
        rinv_s[tid] = TEMP * LOG2E / m;
    }

    f16x8 b[RG][2];
    #pragma unroll
    for (int rg = 0; rg < RG; ++rg) {
        b[rg][0] = *reinterpret_cast<const f16x8*>(&q16[(i0 + rg * 16 + lr) * D + 8 * lg]);
        b[rg][1] = *reinterpret_cast<const f16x8*>(&q16[(i0 + rg * 16 + lr) * D + 32 + 8 * lg]);
    }
    __syncthreads();

    float sm[RG];
    #pragma unroll
    for (int rg = 0; rg < RG; ++rg) sm[rg] = 0.f;

    f16x8 a0[4], a1[4];
    #pragma unroll
    for (int s = 0; s < 3; ++s) {
        const int jr = jbase + s * 16;
        a0[s] = *reinterpret_cast<const f16x8*>(&k16[(jr + lr) * D + 8 * lg]);
        a1[s] = *reinterpret_cast<const f16x8*>(&k16[(jr + lr) * D + 32 + 8 * lg]);
    }

    #pragma unroll
    for (int s = 0; s < 16; ++s) {
        if (s + 3 < 16) {
            const int jr = jbase + (s + 3) * 16;
            a0[(s + 3) & 3] = *reinterpret_cast<const f16x8*>(&k16[(jr + lr) * D + 8 * lg]);
            a1[(s + 3) & 3] = *reinterpret_cast<const f16x8*>(&k16[(jr + lr) * D + 32 + 8 * lg]);
        }
        const float4 r4 = *reinterpret_cast<const float4*>(&rinv_s[s * 16 + lg * 4]);
        #pragma unroll
        for (int rg = 0; rg < RG; ++rg) {
            f32x4 acc = {0.f, 0.f, 0.f, 0.f};
            acc = MFMA16(a0[s & 3], b[rg][0], acc);
            acc = MFMA16(a1[s & 3], b[rg][1], acc);
            sm[rg] += fast_exp2(acc[0] * r4.x) + fast_exp2(acc[1] * r4.y)
                    + fast_exp2(acc[2] * r4.z) + fast_exp2(acc[3] * r4.w);
        }
    }

    #pragma unroll
    for (int rg = 0; rg < RG; ++rg) {
        sm[rg] += __shfl_xor(sm[rg], 16);
        sm[rg] += __shfl_xor(sm[rg], 32);
    }
    if (lane < 16) {
        #pragma unroll
        for (int rg = 0; rg < RG; ++rg)
            Lpart[blockIdx.y * N + i0 + rg * 16 + lr] = sm[rg];
    }
}

// ---------------- Pass 3: paired line-completing PLAIN stores (R23-exact) ----------------
__global__ __launch_bounds__(256) void k_write(
    const _Float16* __restrict__ q16, const _Float16* __restrict__ k16,
    const float* __restrict__ mpart, const float* __restrict__ Lpart,
    float* __restrict__ out)
{
    const int tid  = threadIdx.x;
    const int wave = tid >> 6;
    const int lane = tid & 63;
    const int lr   = lane & 15;
    const int lg   = lane >> 4;
    const int i0b  = blockIdx.x * BROWS;
    const int i0   = i0b + wave * 64;
    const int jbase = blockIdx.y * (N / SPLIT_W);

    __shared__ float rinv_s[N / SPLIT_W];
    __shared__ float linv_s[BROWS];
    {
        float m = mpart[jbase + tid];
        #pragma unroll
        for (int s = 1; s < SPLIT_S; ++s) m = fmaxf(m, mpart[s * N + jbase + tid]);
        rinv_s[tid] = TEMP * LOG2E / m;
        float L = Lpart[i0b + tid];
        #pragma unroll
        for (int s = 1; s < SPLIT_S; ++s) L += Lpart[s * N + i0b + tid];
        linv_s[tid] = 1.f / L;
    }

    f16x8 b[RG][2];
    #pragma unroll
    for (int rg = 0; rg < RG; ++rg) {
        b[rg][0] = *reinterpret_cast<const f16x8*>(&q16[(i0 + rg * 16 + lr) * D + 8 * lg]);
        b[rg][1] = *reinterpret_cast<const f16x8*>(&q16[(i0 + rg * 16 + lr) * D + 32 + 8 * lg]);
    }
    __syncthreads();

    float Lvi[RG];
    #pragma unroll
    for (int rg = 0; rg < RG; ++rg) Lvi[rg] = linv_s[wave * 64 + rg * 16 + lr];

    f16x8 a[2][4];
    a[0][0] = *reinterpret_cast<const f16x8*>(&k16[(jbase + lr) * D + 8 * lg]);
    a[0][1] = *reinterpret_cast<const f16x8*>(&k16[(jbase + lr) * D + 32 + 8 * lg]);
    a[0][2] = *reinterpret_cast<const f16x8*>(&k16[(jbase + 16 + lr) * D + 8 * lg]);
    a[0][3] = *reinterpret_cast<const f16x8*>(&k16[(jbase + 16 + lr) * D + 32 + 8 * lg]);

    #pragma unroll
    for (int s2 = 0; s2 < 8; ++s2) {
        const int p = s2 & 1;
        if (s2 + 1 < 8) {
            const int jn = jbase + (s2 + 1) * 32;
            a[1 - p][0] = *reinterpret_cast<const f16x8*>(&k16[(jn + lr) * D + 8 * lg]);
            a[1 - p][1] = *reinterpret_cast<const f16x8*>(&k16[(jn + lr) * D + 32 + 8 * lg]);
            a[1 - p][2] = *reinterpret_cast<const f16x8*>(&k16[(jn + 16 + lr) * D + 8 * lg]);
            a[1 - p][3] = *reinterpret_cast<const f16x8*>(&k16[(jn + 16 + lr) * D + 32 + 8 * lg]);
        }
        const int j0 = jbase + s2 * 32;
        const float4 r40 = *reinterpret_cast<const float4*>(&rinv_s[s2 * 32 + lg * 4]);
        const float4 r41 = *reinterpret_cast<const float4*>(&rinv_s[s2 * 32 + 16 + lg * 4]);
        #pragma unroll
        for (int rg = 0; rg < RG; ++rg) {
            f32x4 acc0 = {0.f, 0.f, 0.f, 0.f};
            acc0 = MFMA16(a[p][0], b[rg][0], acc0);
            acc0 = MFMA16(a[p][1], b[rg][1], acc0);
            f32x4 acc1 = {0.f, 0.f, 0.f, 0.f};
            acc1 = MFMA16(a[p][2], b[rg][0], acc1);
            acc1 = MFMA16(a[p][3], b[rg][1], acc1);
            float4 o0, o1;
            o0.x = fast_exp2(acc0[0] * r40.x) * Lvi[rg];
            o0.y = fast_exp2(acc0[1] * r40.y) * Lvi[rg];
            o0.z = fast_exp2(acc0[2] * r40.z) * Lvi[rg];
            o0.w = fast_exp2(acc0[3] * r40.w) * Lvi[rg];
            o1.x = fast_exp2(acc1[0] * r41.x) * Lvi[rg];
            o1.y = fast_exp2(acc1[1] * r41.y) * Lvi[rg];
            o1.z = fast_exp2(acc1[2] * r41.z) * Lvi[rg];
            o1.w = fast_exp2(acc1[3] * r41.w) * Lvi[rg];
            float* rowp = out + (size_t)(i0 + rg * 16 + lr) * N + j0;
            *reinterpret_cast<float4*>(rowp + lg * 4)      = o0;
            *reinterpret_cast<float4*>(rowp + 16 + lg * 4) = o1;
        }
    }
}

extern "C" void kernel_launch(void* const* d_in, const int* in_sizes, int n_in,
                              void* d_out, int out_size, void* d_ws, size_t ws_size,
                              hipStream_t stream)
{
    const float* x   = (const float*)d_in[0];
    const float* Wq1 = (const float*)d_in[1];
    const float* bq1 = (const float*)d_in[2];
    const float* Wq2 = (const float*)d_in[3];
    const float* bq2 = (const float*)d_in[4];
    const float* Wk1 = (const float*)d_in[5];
    const float* bk1 = (const float*)d_in[6];
    const float* Wk2 = (const float*)d_in[7];
    const float* bk2 = (const float*)d_in[8];

    float* out = (float*)d_out;

    _Float16* q16   = (_Float16*)d_ws;                     // N*D
    _Float16* k16   = q16 + (size_t)N * D;                 // N*D
    _Float16* xhi   = k16 + (size_t)N * D;                 // N*KP
    _Float16* xlo   = xhi + (size_t)N * KP;                // N*KP
    _Float16* w1thi = xlo + (size_t)N * KP;                // 2*64*KP
    _Float16* w1tlo = w1thi + 2 * 64 * KP;
    _Float16* w2thi = w1tlo + 2 * 64 * KP;                 // 2*64*64
    _Float16* w2tlo = w2thi + 2 * 64 * 64;
    float* mpart = (float*)(w2tlo + 2 * 64 * 64);          // SPLIT_S*N
    float* Lpart = mpart + (size_t)SPLIT_S * N;            // SPLIT_S*N

    k_prep_x<<<N / 4, 256, 0, stream>>>(x, xhi, xlo);
    k_prep_w<<<1, 256, 0, stream>>>(Wq1, Wk1, Wq2, Wk2, w1thi, w1tlo, w2thi, w2tlo);
    k_mlp2  <<<dim3(N / 16, 2), 64, 0, stream>>>(xhi, xlo, w1thi, w1tlo, w2thi, w2tlo,
                                                 bq1, bk1, bq2, bk2, q16, k16);
    k_max   <<<dim3(N / BROWS, SPLIT_S), 256, 0, stream>>>(q16, k16, mpart);
    k_sumL  <<<dim3(N / BROWS, SPLIT_S), 256, 0, stream>>>(q16, k16, mpart, Lpart);
    k_write <<<dim3(N / BROWS, SPLIT_W), 256, 0, stream>>>(q16, k16, mpart, Lpart, out);
}